// Round 1
// baseline (910.240 us; speedup 1.0000x reference)
//
#include <hip/hip_runtime.h>

// 4-D "same" conv, direct form.
// x:      (B=8, CIN=8, 24,24,24,24) fp32
// weight: (COUT=16, 81*8) fp32, kernel-major / channel-minor
// bias:   (16,) fp32
// out:    (B=8, COUT=16, 24,24,24,24) fp32
//
// One thread per (b, p1..p4) output position, computing all 16 couts.
// Weight indices are wave-uniform -> scalar loads; x loads coalesced in s4.

#define SDIM 24
#define SP   (SDIM * SDIM * SDIM * SDIM)   // 331776
#define CIN  8
#define COUT 16
#define BATCH 8
#define KW   648                            // 81 * CIN

__global__ __launch_bounds__(256) void conv4d_direct(
    const float* __restrict__ x,
    const float* __restrict__ w,
    const float* __restrict__ bias,
    float* __restrict__ out)
{
    int t = blockIdx.x * blockDim.x + threadIdx.x;   // 0 .. B*SP-1 (exact multiple of 256)
    int b = t / SP;
    int p = t - b * SP;
    int p4 = p % SDIM;
    int tmp = p / SDIM;
    int p3 = tmp % SDIM;
    tmp /= SDIM;
    int p2 = tmp % SDIM;
    int p1 = tmp / SDIM;

    float acc[COUT];
    #pragma unroll
    for (int o = 0; o < COUT; ++o) acc[o] = bias[o];

    const float* xb = x + (size_t)b * CIN * SP;

    #pragma unroll 1
    for (int k1 = 0; k1 < 3; ++k1) {
        unsigned q1 = (unsigned)(p1 + k1 - 1);
        if (q1 >= SDIM) continue;
        #pragma unroll 1
        for (int k2 = 0; k2 < 3; ++k2) {
            unsigned q2 = (unsigned)(p2 + k2 - 1);
            if (q2 >= SDIM) continue;
            #pragma unroll 1
            for (int k3 = 0; k3 < 3; ++k3) {
                unsigned q3 = (unsigned)(p3 + k3 - 1);
                if (q3 >= SDIM) continue;
                int base123 = (((int)q1 * SDIM + (int)q2) * SDIM + (int)q3) * SDIM;
                int kflat123 = ((k1 * 3 + k2) * 3 + k3) * 3;
                #pragma unroll 1
                for (int k4 = 0; k4 < 3; ++k4) {
                    unsigned q4 = (unsigned)(p4 + k4 - 1);
                    if (q4 >= SDIM) continue;
                    int q = base123 + (int)q4;

                    float xv[CIN];
                    #pragma unroll
                    for (int c = 0; c < CIN; ++c)
                        xv[c] = xb[c * SP + q];

                    const float* wp = w + (kflat123 + k4) * CIN;  // wave-uniform address
                    #pragma unroll
                    for (int o = 0; o < COUT; ++o) {
                        #pragma unroll
                        for (int c = 0; c < CIN; ++c)
                            acc[o] = fmaf(xv[c], wp[o * KW + c], acc[o]);
                    }
                }
            }
        }
    }

    float* ob = out + (size_t)b * COUT * SP + p;
    #pragma unroll
    for (int o = 0; o < COUT; ++o)
        ob[o * SP] = acc[o];
}

extern "C" void kernel_launch(void* const* d_in, const int* in_sizes, int n_in,
                              void* d_out, int out_size, void* d_ws, size_t ws_size,
                              hipStream_t stream)
{
    const float* x    = (const float*)d_in[0];
    const float* w    = (const float*)d_in[1];
    const float* bias = (const float*)d_in[2];
    float* out        = (float*)d_out;

    const int total = BATCH * SP;            // 2,654,208
    const int block = 256;
    const int grid  = total / block;         // 10368, exact

    hipLaunchKernelGGL(conv4d_direct, dim3(grid), dim3(block), 0, stream,
                       x, w, bias, out);
}

// Round 2
// 513.769 us; speedup vs baseline: 1.7717x; 1.7717x over previous
//
#include <hip/hip_runtime.h>

// 4-D "same" conv as implicit GEMM on bf16 MFMA.
//   M = COUT = 16, N = 16 positions/wave, K = 81 taps * 8 cin = 648 -> pad 672.
//   mfma_f32_16x16x32_bf16: 21 K-chunks; chunk = 4 taps (quad) x 8 cin (j).
// Prepass 1: weights -> A-frag order Wpack[chunk][lane][8] bf16 (zero-pad k>=648).
// Prepass 2: x (B,CIN,SP) fp32 -> xT (B,SP,CIN) bf16 so a lane's B-frag is one 16B load.
// OOB taps: load address redirected to a zeroed 16B slot in ws (cndmask, no branch).

#define SDIM  24
#define SP    (SDIM * SDIM * SDIM * SDIM)   // 331776
#define CIN   8
#define COUT  16
#define BATCH 8
#define KW    648                            // 81 * CIN
#define NCHUNK 21                            // ceil(648/32)

#define ZERO_OFF 0
#define WPK_OFF  256
#define XT_OFF   32768
#define XT_BYTES ((size_t)BATCH * SP * CIN * 2)          // 42,467,328
#define WS_NEEDED (XT_OFF + XT_BYTES)

typedef __attribute__((ext_vector_type(8))) short short8;   // 8 bf16 = 4 VGPRs
typedef __attribute__((ext_vector_type(4))) float f32x4;

static __device__ __forceinline__ unsigned short f2bf(float f) {
    unsigned u = __builtin_bit_cast(unsigned, f);
    u = (u + 0x7fffu + ((u >> 16) & 1u)) >> 16;          // RNE
    return (unsigned short)u;
}

// ---------- prepass 1: pack weights + zero slot ----------
__global__ __launch_bounds__(256) void pack_weights(
    const float* __restrict__ w, unsigned char* __restrict__ ws)
{
    int t = blockIdx.x * 256 + threadIdx.x;              // 0..1535
    if (t == 1344) {                                     // zero slot (16 B)
        short8 z = {0,0,0,0,0,0,0,0};
        *(short8*)(ws + ZERO_OFF) = z;
    }
    if (t >= NCHUNK * 64) return;
    int chunk = t >> 6;
    int lane  = t & 63;
    int m     = lane & 15;
    int quad  = lane >> 4;
    unsigned short v[8];
    #pragma unroll
    for (int j = 0; j < 8; ++j) {
        int k = chunk * 32 + quad * 8 + j;
        float f = (k < KW) ? w[m * KW + k] : 0.0f;
        v[j] = f2bf(f);
    }
    short8* dst = (short8*)(ws + WPK_OFF);
    short8 pk;
    #pragma unroll
    for (int j = 0; j < 8; ++j) pk[j] = (short)v[j];
    dst[chunk * 64 + lane] = pk;
}

// ---------- prepass 2: x (B,CIN,SP) fp32 -> xT (B,SP,CIN) bf16 ----------
__global__ __launch_bounds__(256) void transpose_x(
    const float* __restrict__ x, unsigned char* __restrict__ ws)
{
    int idx = blockIdx.x * 256 + threadIdx.x;            // exact: B*SP/256 blocks
    int b = idx / SP;
    int p = idx - b * SP;
    const float* xb = x + (size_t)b * CIN * SP + p;
    short8 pk;
    #pragma unroll
    for (int c = 0; c < CIN; ++c) pk[c] = (short)f2bf(xb[c * SP]);
    ((short8*)(ws + XT_OFF))[idx] = pk;
}

// ---------- main: implicit GEMM ----------
__global__ __launch_bounds__(256) void conv4d_mfma(
    const unsigned char* __restrict__ ws,
    const float* __restrict__ bias,
    float* __restrict__ out)
{
    const int lane = threadIdx.x & 63;
    const int wave = threadIdx.x >> 6;
    const int col  = lane & 15;
    const int quad = lane >> 4;

    const int tile = blockIdx.x * 4 + wave;              // 165,888 tiles
    const int pg   = tile * 16 + col;                    // global position
    const int b    = pg / SP;
    const int p    = pg - b * SP;
    int r  = p;
    const int p4 = r % SDIM; r /= SDIM;
    const int p3 = r % SDIM; r /= SDIM;
    const int p2 = r % SDIM;
    const int p1 = r / SDIM;

    // A fragments: same for every wave, L2-resident
    const short8* wpk = (const short8*)(ws + WPK_OFF);
    short8 afrag[NCHUNK];
    #pragma unroll
    for (int c = 0; c < NCHUNK; ++c) afrag[c] = wpk[c * 64 + lane];

    const short8* xT   = (const short8*)(ws + XT_OFF);
    const short8* zslt = (const short8*)(ws + ZERO_OFF);
    const short8* xTb  = xT + (size_t)b * SP;

    f32x4 acc = {0.f, 0.f, 0.f, 0.f};

    #pragma unroll
    for (int c = 0; c < NCHUNK; ++c) {
        int tap = c * 4 + quad;
        int k1 = tap / 27; int rem = tap - k1 * 27;
        int k2 = rem / 9;  rem -= k2 * 9;
        int k3 = rem / 3;
        int k4 = rem - k3 * 3;
        int q1 = p1 + k1 - 1, q2 = p2 + k2 - 1, q3 = p3 + k3 - 1, q4 = p4 + k4 - 1;
        bool valid = ((unsigned)q1 < (unsigned)SDIM) & ((unsigned)q2 < (unsigned)SDIM) &
                     ((unsigned)q3 < (unsigned)SDIM) & ((unsigned)q4 < (unsigned)SDIM);
        int q = ((q1 * SDIM + q2) * SDIM + q3) * SDIM + q4;
        const short8* src = valid ? (xTb + q) : zslt;
        short8 bfrag = *src;
        acc = __builtin_amdgcn_mfma_f32_16x16x32_bf16(afrag[c], bfrag, acc, 0, 0, 0);
    }

    // epilogue: D[row=quad*4+reg][col] -> out[b][row][p] ; add bias
    f32x4 b4 = *(const f32x4*)(bias + quad * 4);
    float* obase = out + ((size_t)b * COUT + quad * 4) * SP + p;
    #pragma unroll
    for (int reg = 0; reg < 4; ++reg)
        obase[(size_t)reg * SP] = acc[reg] + b4[reg];
}

// ---------- fallback (round-1 direct fp32) if ws too small ----------
__global__ __launch_bounds__(256) void conv4d_direct(
    const float* __restrict__ x, const float* __restrict__ w,
    const float* __restrict__ bias, float* __restrict__ out)
{
    int t = blockIdx.x * blockDim.x + threadIdx.x;
    int b = t / SP;
    int p = t - b * SP;
    int p4 = p % SDIM; int tmp = p / SDIM;
    int p3 = tmp % SDIM; tmp /= SDIM;
    int p2 = tmp % SDIM; int p1 = tmp / SDIM;
    float acc[COUT];
    #pragma unroll
    for (int o = 0; o < COUT; ++o) acc[o] = bias[o];
    const float* xb = x + (size_t)b * CIN * SP;
    for (int k1 = 0; k1 < 3; ++k1) {
        unsigned q1 = (unsigned)(p1 + k1 - 1); if (q1 >= SDIM) continue;
        for (int k2 = 0; k2 < 3; ++k2) {
            unsigned q2 = (unsigned)(p2 + k2 - 1); if (q2 >= SDIM) continue;
            for (int k3 = 0; k3 < 3; ++k3) {
                unsigned q3 = (unsigned)(p3 + k3 - 1); if (q3 >= SDIM) continue;
                int base123 = (((int)q1 * SDIM + (int)q2) * SDIM + (int)q3) * SDIM;
                int kf = ((k1 * 3 + k2) * 3 + k3) * 3;
                for (int k4 = 0; k4 < 3; ++k4) {
                    unsigned q4 = (unsigned)(p4 + k4 - 1); if (q4 >= SDIM) continue;
                    int q = base123 + (int)q4;
                    float xv[CIN];
                    #pragma unroll
                    for (int c = 0; c < CIN; ++c) xv[c] = xb[c * SP + q];
                    const float* wp = w + (kf + k4) * CIN;
                    #pragma unroll
                    for (int o = 0; o < COUT; ++o)
                        #pragma unroll
                        for (int c = 0; c < CIN; ++c)
                            acc[o] = fmaf(xv[c], wp[o * KW + c], acc[o]);
                }
            }
        }
    }
    float* ob = out + (size_t)b * COUT * SP + p;
    #pragma unroll
    for (int o = 0; o < COUT; ++o) ob[o * SP] = acc[o];
}

extern "C" void kernel_launch(void* const* d_in, const int* in_sizes, int n_in,
                              void* d_out, int out_size, void* d_ws, size_t ws_size,
                              hipStream_t stream)
{
    const float* x    = (const float*)d_in[0];
    const float* w    = (const float*)d_in[1];
    const float* bias = (const float*)d_in[2];
    float* out        = (float*)d_out;

    if (ws_size < WS_NEEDED) {                           // insurance
        const int total = BATCH * SP;
        hipLaunchKernelGGL(conv4d_direct, dim3(total / 256), dim3(256), 0, stream,
                           x, w, bias, out);
        return;
    }

    unsigned char* ws = (unsigned char*)d_ws;

    hipLaunchKernelGGL(pack_weights, dim3(6), dim3(256), 0, stream, w, ws);
    hipLaunchKernelGGL(transpose_x, dim3(BATCH * SP / 256), dim3(256), 0, stream, x, ws);

    const int tiles  = BATCH * SP / 16;                  // 165,888
    const int blocks = tiles / 4;                        // 41,472 (4 waves/block)
    hipLaunchKernelGGL(conv4d_mfma, dim3(blocks), dim3(256), 0, stream,
                       (const unsigned char*)ws, bias, out);
}

// Round 3
// 361.336 us; speedup vs baseline: 2.5191x; 1.4219x over previous
//
#include <hip/hip_runtime.h>
#include <hip/hip_bf16.h>

// 4-D "same" conv as implicit GEMM on bf16 MFMA.
//   M = COUT = 16, N = 16 positions/wave, K = 648 -> pad 672 (21 chunks of 32).
//   Each wave now processes the SAME 16 positions for 4 BATCHES:
//   tap decomposition/validity/q computed once per chunk, shared by 4 gathers+MFMAs.
// Prepass 1: weights -> A-frag order Wpack[chunk][lane][8] bf16 (zero-pad k>=648).
// Prepass 2: x (B,CIN,SP) fp32 -> xT (B,SP,CIN) bf16 via HW packed cvt
//            (__float22bfloat162_rn), 2 positions/thread.

#define SDIM  24
#define SP    (SDIM * SDIM * SDIM * SDIM)   // 331776
#define CIN   8
#define COUT  16
#define BATCH 8
#define KW    648                            // 81 * CIN
#define NCHUNK 21                            // ceil(648/32)
#define NB    4                              // batches per wave
#define PTILES (SP / 16)                     // 20736 position tiles

#define ZERO_OFF 0
#define WPK_OFF  256
#define XT_OFF   32768
#define XT_BYTES ((size_t)BATCH * SP * CIN * 2)          // 42,467,328
#define WS_NEEDED (XT_OFF + XT_BYTES)

typedef __attribute__((ext_vector_type(8))) short short8;   // 8 bf16 = 4 VGPRs
typedef __attribute__((ext_vector_type(4))) float f32x4;

static __device__ __forceinline__ unsigned short f2bf(float f) {
    unsigned u = __builtin_bit_cast(unsigned, f);
    u = (u + 0x7fffu + ((u >> 16) & 1u)) >> 16;          // RNE
    return (unsigned short)u;
}

// ---------- prepass 1: pack weights + zero slot ----------
__global__ __launch_bounds__(256) void pack_weights(
    const float* __restrict__ w, unsigned char* __restrict__ ws)
{
    int t = blockIdx.x * 256 + threadIdx.x;              // 0..1535
    if (t == 1344) {                                     // zero slot (16 B)
        short8 z = {0,0,0,0,0,0,0,0};
        *(short8*)(ws + ZERO_OFF) = z;
    }
    if (t >= NCHUNK * 64) return;
    int chunk = t >> 6;
    int lane  = t & 63;
    int m     = lane & 15;
    int quad  = lane >> 4;
    short8 pk;
    #pragma unroll
    for (int j = 0; j < 8; ++j) {
        int k = chunk * 32 + quad * 8 + j;
        float f = (k < KW) ? w[m * KW + k] : 0.0f;
        pk[j] = (short)f2bf(f);
    }
    ((short8*)(ws + WPK_OFF))[chunk * 64 + lane] = pk;
}

// ---------- prepass 2: x (B,CIN,SP) fp32 -> xT (B,SP,CIN) bf16 ----------
// 2 positions per thread; packed HW bf16 convert.
__global__ __launch_bounds__(256) void transpose_x(
    const float* __restrict__ x, unsigned char* __restrict__ ws)
{
    int idx = blockIdx.x * 256 + threadIdx.x;            // pair index
    int b  = idx / (SP / 2);
    int pp = idx - b * (SP / 2);
    int p  = pp * 2;
    const float* xb = x + (size_t)b * CIN * SP + p;

    float2 v[CIN];
    #pragma unroll
    for (int c = 0; c < CIN; ++c)
        v[c] = *(const float2*)(xb + (size_t)c * SP);

    union { __hip_bfloat162 h2[4]; short8 s8; } u0, u1;
    #pragma unroll
    for (int i = 0; i < 4; ++i) {
        float2 a = make_float2(v[2 * i].x, v[2 * i + 1].x);   // position p
        float2 bq = make_float2(v[2 * i].y, v[2 * i + 1].y);  // position p+1
        u0.h2[i] = __float22bfloat162_rn(a);
        u1.h2[i] = __float22bfloat162_rn(bq);
    }
    short8* dst = (short8*)(ws + XT_OFF) + ((size_t)b * SP + p);
    dst[0] = u0.s8;
    dst[1] = u1.s8;
}

// ---------- main: implicit GEMM, 4 batches per wave ----------
__global__ __launch_bounds__(256) void conv4d_mfma(
    const unsigned char* __restrict__ ws,
    const float* __restrict__ bias,
    float* __restrict__ out)
{
    const int lane = threadIdx.x & 63;
    const int wave = threadIdx.x >> 6;
    const int col  = lane & 15;
    const int quad = lane >> 4;

    int W = blockIdx.x * 4 + wave;                       // 0..41471
    W = __builtin_amdgcn_readfirstlane(W);               // wave-uniform -> SGPR
    const int pt = W % PTILES;                           // position tile
    const int g  = W / PTILES;                           // batch group 0..1

    const int p = pt * 16 + col;
    int r = p;
    const int p4 = r % SDIM; r /= SDIM;
    const int p3 = r % SDIM; r /= SDIM;
    const int p2 = r % SDIM;
    const int p1 = r / SDIM;

    const short8* wpk  = (const short8*)(ws + WPK_OFF);
    const short8* xT   = (const short8*)(ws + XT_OFF);
    const short8* zslt = (const short8*)(ws + ZERO_OFF);

    const short8* xb[NB];
    #pragma unroll
    for (int t = 0; t < NB; ++t)
        xb[t] = xT + (size_t)(g * NB + t) * SP;

    f32x4 acc[NB];
    #pragma unroll
    for (int t = 0; t < NB; ++t) acc[t] = (f32x4){0.f, 0.f, 0.f, 0.f};

    #pragma unroll
    for (int c = 0; c < NCHUNK; ++c) {
        short8 afrag = wpk[c * 64 + lane];

        int tap = c * 4 + quad;
        int k1 = tap / 27; int rem = tap - k1 * 27;
        int k2 = rem / 9;  rem -= k2 * 9;
        int k3 = rem / 3;
        int k4 = rem - k3 * 3;
        int q1 = p1 + k1 - 1, q2 = p2 + k2 - 1, q3 = p3 + k3 - 1, q4 = p4 + k4 - 1;
        bool valid = ((unsigned)q1 < (unsigned)SDIM) & ((unsigned)q2 < (unsigned)SDIM) &
                     ((unsigned)q3 < (unsigned)SDIM) & ((unsigned)q4 < (unsigned)SDIM);
        int q = ((q1 * SDIM + q2) * SDIM + q3) * SDIM + q4;

        short8 bf[NB];
        #pragma unroll
        for (int t = 0; t < NB; ++t) {
            const short8* src = valid ? (xb[t] + q) : zslt;
            bf[t] = *src;
        }
        #pragma unroll
        for (int t = 0; t < NB; ++t)
            acc[t] = __builtin_amdgcn_mfma_f32_16x16x32_bf16(afrag, bf[t], acc[t], 0, 0, 0);
    }

    // epilogue: D[row=quad*4+reg][col] -> out[b][row][p] ; add bias
    f32x4 b4 = *(const f32x4*)(bias + quad * 4);
    #pragma unroll
    for (int t = 0; t < NB; ++t) {
        float* obase = out + ((size_t)(g * NB + t) * COUT + quad * 4) * SP + p;
        #pragma unroll
        for (int reg = 0; reg < 4; ++reg)
            obase[(size_t)reg * SP] = acc[t][reg] + b4[reg];
    }
}

// ---------- fallback (direct fp32) if ws too small ----------
__global__ __launch_bounds__(256) void conv4d_direct(
    const float* __restrict__ x, const float* __restrict__ w,
    const float* __restrict__ bias, float* __restrict__ out)
{
    int t = blockIdx.x * blockDim.x + threadIdx.x;
    int b = t / SP;
    int p = t - b * SP;
    int p4 = p % SDIM; int tmp = p / SDIM;
    int p3 = tmp % SDIM; tmp /= SDIM;
    int p2 = tmp % SDIM; int p1 = tmp / SDIM;
    float acc[COUT];
    #pragma unroll
    for (int o = 0; o < COUT; ++o) acc[o] = bias[o];
    const float* xb = x + (size_t)b * CIN * SP;
    for (int k1 = 0; k1 < 3; ++k1) {
        unsigned q1 = (unsigned)(p1 + k1 - 1); if (q1 >= SDIM) continue;
        for (int k2 = 0; k2 < 3; ++k2) {
            unsigned q2 = (unsigned)(p2 + k2 - 1); if (q2 >= SDIM) continue;
            for (int k3 = 0; k3 < 3; ++k3) {
                unsigned q3 = (unsigned)(p3 + k3 - 1); if (q3 >= SDIM) continue;
                int base123 = (((int)q1 * SDIM + (int)q2) * SDIM + (int)q3) * SDIM;
                int kf = ((k1 * 3 + k2) * 3 + k3) * 3;
                for (int k4 = 0; k4 < 3; ++k4) {
                    unsigned q4 = (unsigned)(p4 + k4 - 1); if (q4 >= SDIM) continue;
                    int q = base123 + (int)q4;
                    float xv[CIN];
                    #pragma unroll
                    for (int c = 0; c < CIN; ++c) xv[c] = xb[c * SP + q];
                    const float* wp = w + (kf + k4) * CIN;
                    #pragma unroll
                    for (int o = 0; o < COUT; ++o)
                        #pragma unroll
                        for (int c = 0; c < CIN; ++c)
                            acc[o] = fmaf(xv[c], wp[o * KW + c], acc[o]);
                }
            }
        }
    }
    float* ob = out + (size_t)b * COUT * SP + p;
    #pragma unroll
    for (int o = 0; o < COUT; ++o) ob[o * SP] = acc[o];
}

extern "C" void kernel_launch(void* const* d_in, const int* in_sizes, int n_in,
                              void* d_out, int out_size, void* d_ws, size_t ws_size,
                              hipStream_t stream)
{
    const float* x    = (const float*)d_in[0];
    const float* w    = (const float*)d_in[1];
    const float* bias = (const float*)d_in[2];
    float* out        = (float*)d_out;

    if (ws_size < WS_NEEDED) {                           // insurance
        const int total = BATCH * SP;
        hipLaunchKernelGGL(conv4d_direct, dim3(total / 256), dim3(256), 0, stream,
                           x, w, bias, out);
        return;
    }

    unsigned char* ws = (unsigned char*)d_ws;

    hipLaunchKernelGGL(pack_weights, dim3(6), dim3(256), 0, stream, w, ws);

    const int pair_total = BATCH * SP / 2;               // 1,327,104
    hipLaunchKernelGGL(transpose_x, dim3(pair_total / 256), dim3(256), 0, stream, x, ws);

    const int waves  = (BATCH / NB) * PTILES;            // 41,472
    const int blocks = waves / 4;                        // 10,368
    hipLaunchKernelGGL(conv4d_mfma, dim3(blocks), dim3(256), 0, stream,
                       (const unsigned char*)ws, bias, out);
}